// Round 7
// baseline (52.929 us; speedup 1.0000x reference)
//
#include <hip/hip_runtime.h>
#include <hip/hip_bf16.h>

// 25-level wavelet decomposition, f: 2^25 f32, P: [25,2] f32.
// out layout: out[0]=final approx; detail level j occupies [2^(24-j), 2^(25-j)).
//
// Two kernels. R6: CHUNK 16384 -> 8192 (grid 2048 -> 4096 = 2 residency
// waves) so late blocks' streaming overlaps early blocks' LDS ping-pong;
// with grid == 1 residency wave, all blocks hit the ping-pong tail in
// lockstep and HBM idled.
//
// Kernel 1: block owns 2^13 elements. Levels 0-2 in registers off float4
//   loads (details via nt stores -- R5: neutral-to-slightly-positive, keep);
//   levels 3-12 ping-pong in 6 KB LDS (8 blocks/CU). Level-12 approx ->
//   out[blk] (temp; [0,4096) fully rewritten by kernel 2).
// Kernel 2: one 512-thread block finishes levels 13-24 (4096 values).
//
// HISTORY:
//  R2-R4: 465us regression = __threadfence() L2 writeback storm (not nt).
//  R4: fused last-block election loses ~10us to 2048 same-line atomics.
//  R5: nt stores alone neutral (52.6 vs 53.8); FETCH unchanged ~66MB.

#define CHUNK 8192
#define THREADS 256
#define NBLOCKS ((1 << 25) / CHUNK)   // 4096
#define K2THREADS 512

typedef __attribute__((ext_vector_type(4))) float f4_t;
typedef __attribute__((ext_vector_type(2))) float f2_t;

__device__ __forceinline__ void nt_store4(float4 v, float4* p) {
    f4_t t = {v.x, v.y, v.z, v.w};
    __builtin_nontemporal_store(t, (f4_t*)p);
}
__device__ __forceinline__ void nt_store2(float2 v, float2* p) {
    f2_t t = {v.x, v.y};
    __builtin_nontemporal_store(t, (f2_t*)p);
}
__device__ __forceinline__ void nt_store1(float v, float* p) {
    __builtin_nontemporal_store(v, p);
}

__device__ __forceinline__ void level_params(const float* __restrict__ P, int j,
                                             float& hx, float& hy) {
    float px = P[2 * j], py = P[2 * j + 1];
    float n = fmaxf(sqrtf(px * px + py * py), 1e-12f);
    hx = px / n;  // phi_x
    hy = py / n;  // phi_y   (psi = (phi_y, -phi_x))
}

__global__ __launch_bounds__(THREADS, 8)
void wave_lvl0_12(const float* __restrict__ f, const float* __restrict__ P,
                  float* __restrict__ out) {
    __shared__ float A[CHUNK / 8];   // 1024 floats, 4 KB
    __shared__ float B[CHUNK / 16];  // 512 floats, 2 KB
    const int tid = threadIdx.x;
    const int blk = blockIdx.x;

    float hx0, hy0, hx1, hy1, hx2, hy2;
    level_params(P, 0, hx0, hy0);
    level_params(P, 1, hx1, hy1);
    level_params(P, 2, hx2, hy2);

    // ---- levels 0..2 in registers: 8 consecutive elements per thread-iter ----
    const float4* in4 = reinterpret_cast<const float4*>(f) + (size_t)blk * (CHUNK / 4);
    float4* d0out = reinterpret_cast<float4*>(out + (1 << 24) + (size_t)blk * (CHUNK / 2));
    float2* d1out = reinterpret_cast<float2*>(out + (1 << 23) + (size_t)blk * (CHUNK / 4));
    float*  d2out = out + (1 << 22) + (size_t)blk * (CHUNK / 8);

#pragma unroll
    for (int t = 0; t < CHUNK / 8 / THREADS; ++t) {   // 4 iters
        int g = tid + t * THREADS;                    // group of 8 elements
        float4 u = in4[2 * g];
        float4 v = in4[2 * g + 1];
        // level 0
        float d0 = u.x * hy0 - u.y * hx0, a0 = u.x * hx0 + u.y * hy0;
        float d1 = u.z * hy0 - u.w * hx0, a1 = u.z * hx0 + u.w * hy0;
        float d2 = v.x * hy0 - v.y * hx0, a2 = v.x * hx0 + v.y * hy0;
        float d3 = v.z * hy0 - v.w * hx0, a3 = v.z * hx0 + v.w * hy0;
        nt_store4(make_float4(d0, d1, d2, d3), &d0out[g]);
        // level 1
        float e0 = a0 * hy1 - a1 * hx1, b0 = a0 * hx1 + a1 * hy1;
        float e1 = a2 * hy1 - a3 * hx1, b1 = a2 * hx1 + a3 * hy1;
        nt_store2(make_float2(e0, e1), &d1out[g]);
        // level 2
        nt_store1(b0 * hy2 - b1 * hx2, &d2out[g]);
        A[g] = b0 * hx2 + b1 * hy2;
    }
    __syncthreads();

    // ---- levels 3..12: LDS ping-pong (1024 -> 1) ----
    float* cur = A;
    float* nxt = B;
    for (int j = 3; j <= 12; ++j) {
        int p = CHUNK >> (j + 1);    // pairs: j=3 -> 512 ... j=12 -> 1
        float hx, hy;
        level_params(P, j, hx, hy);
        float* dout = out + (1 << (24 - j)) + (size_t)blk * p;
        for (int k = tid; k < p; k += THREADS) {
            float x = cur[2 * k], y = cur[2 * k + 1];
            nt_store1(x * hy - y * hx, &dout[k]);
            nxt[k] = x * hx + y * hy;
        }
        __syncthreads();
        float* tmp = cur; cur = nxt; nxt = tmp;
    }

    if (tid == 0) out[blk] = cur[0];
}

__global__ __launch_bounds__(K2THREADS)
void wave_lvl13_24(const float* __restrict__ P, float* __restrict__ out) {
    __shared__ float A[NBLOCKS];      // 4096 floats, 16 KB
    __shared__ float B[NBLOCKS / 2];  // 2048 floats, 8 KB
    const int tid = threadIdx.x;

    for (int k = tid; k < NBLOCKS; k += K2THREADS) A[k] = out[k];
    __syncthreads();

    float* cur = A;
    float* nxt = B;
    for (int j = 13; j <= 18; ++j) {  // 2048 .. 64 pairs
        int p = 1 << (24 - j);
        float hx, hy;
        level_params(P, j, hx, hy);
        float* dout = out + p;        // detail band [p, 2p)
        for (int k = tid; k < p; k += K2THREADS) {
            float x = cur[2 * k], y = cur[2 * k + 1];
            dout[k] = x * hy - y * hx;
            nxt[k]  = x * hx + y * hy;
        }
        __syncthreads();
        float* tmp = cur; cur = nxt; nxt = tmp;
    }

    // levels 19..24 (32 pairs .. 1 pair) in wave 0 via shuffles
    if (tid < 64) {
        float v = cur[tid];           // 64 remaining values, 1/lane
        for (int j = 19; j <= 24; ++j) {
            int p = 1 << (24 - j);    // 32,16,8,4,2,1
            float hx, hy;
            level_params(P, j, hx, hy);
            float x = __shfl(v, 2 * tid, 64);
            float y = __shfl(v, 2 * tid + 1, 64);
            if (tid < p) out[p + tid] = x * hy - y * hx;
            v = x * hx + y * hy;
        }
        if (tid == 0) out[0] = v;
    }
}

extern "C" void kernel_launch(void* const* d_in, const int* in_sizes, int n_in,
                              void* d_out, int out_size, void* d_ws, size_t ws_size,
                              hipStream_t stream) {
    const float* f = (const float*)d_in[0];
    const float* P = (const float*)d_in[1];
    float* out = (float*)d_out;

    wave_lvl0_12<<<NBLOCKS, THREADS, 0, stream>>>(f, P, out);
    wave_lvl13_24<<<1, K2THREADS, 0, stream>>>(P, out);
}